// Round 6
// baseline (157.647 us; speedup 1.0000x reference)
//
#include <hip/hip_runtime.h>

#define NN  1024
#define EMB 128
#define HID 128

typedef __attribute__((ext_vector_type(2))) float float2v;
typedef __attribute__((ext_vector_type(4))) float float4v;
typedef __attribute__((ext_vector_type(8))) float float8v;
typedef __attribute__((ext_vector_type(8))) short short8;
typedef __attribute__((ext_vector_type(4))) __bf16 bf16x4;
typedef __attribute__((ext_vector_type(8))) __bf16 bf16x8;

__device__ __forceinline__ float2v lo2(float4v v) { float2v r; r[0] = v[0]; r[1] = v[1]; return r; }
__device__ __forceinline__ float2v hi2(float4v v) { float2v r; r[0] = v[2]; r[1] = v[3]; return r; }

__device__ __forceinline__ short8 to_bf16x8_pk(float2v al, float2v ah, float2v bl, float2v bh) {
  float8v f = {al[0], al[1], ah[0], ah[1], bl[0], bl[1], bh[0], bh[1]};
  bf16x8 r = __builtin_convertvector(f, bf16x8);   // v_cvt_pk_bf16_f32 x4
  return __builtin_bit_cast(short8, r);
}

__device__ __forceinline__ void store_bf16x4(short* p, float4v v) {
  bf16x4 r = __builtin_convertvector(v, bf16x4);
  *(bf16x4*)p = r;
}

// tanh-form GELU on 4 elements as 2x float2v halves. Same op graph as round 0
// (absmax-identical): ONE v_rcp per 4 elements via shared reciprocal.
// d_i = 1+2^y >= 1, |x|<4.5 => product < 2^80: no overflow.
__device__ __forceinline__ void gelu4pk(float2v xl, float2v xh,
                                        float2v& ol, float2v& oh) {
  float2v x2l = xl * xl;
  float2v x2h = xh * xh;
  float2v tl = x2l * 0.1029432f + 2.3022086f;  // 2*sqrt(2/pi)*log2e*(1+0.044715x^2)
  float2v th = x2h * 0.1029432f + 2.3022086f;
  float2v yl = xl * tl;
  float2v yh = xh * th;
  float2v el, eh;
  el[0] = __builtin_amdgcn_exp2f(yl[0]);
  el[1] = __builtin_amdgcn_exp2f(yl[1]);
  eh[0] = __builtin_amdgcn_exp2f(yh[0]);
  eh[1] = __builtin_amdgcn_exp2f(yh[1]);
  float2v dl = el + 1.0f;
  float2v dh = eh + 1.0f;
  float p01 = dl[0] * dl[1];
  float p23 = dh[0] * dh[1];
  float rall = __builtin_amdgcn_rcpf(p01 * p23);
  float r01 = p23 * rall;                      // 1/(d0*d1)
  float r23 = p01 * rall;                      // 1/(d2*d3)
  float2v rvl, rvh;
  rvl[0] = dl[1] * r01;
  rvl[1] = dl[0] * r01;
  rvh[0] = dh[1] * r23;
  rvh[1] = dh[0] * r23;
  ol = xl - xl * rvl;                          // x*sigmoid(2*inner)
  oh = xh - xh * rvh;
}

__device__ __forceinline__ float4v mfma16(short8 a, short8 b, float4v c) {
  return __builtin_amdgcn_mfma_f32_16x16x32_bf16(a, b, c, 0, 0, 0);
}

// ---------------------------------------------------------------------------
// prep (round-6 restructure: PARALLELISM. Old prep = 264 blocks ~ 1 block/CU,
// latency-bound serial chain => up to ~50 us of the 157 us total. New prep =
// 1088 one-wave blocks; identical arithmetic, 4x finer tiles):
//   blocks 0..511    -> A-part: Abuf[j0..j0+15, g0..g0+15] = z1·W1a + b1
//   blocks 512..1023 -> B-part: Bbuf[i0..i0+15, g0..g0+15] = z2·W1b
//   blocks 1024..1087-> W2f: bf16(W2) pre-swizzled, half-major frag order
// Same MFMA op order, same bf16 RNE conversions -> bit-identical outputs.
// ---------------------------------------------------------------------------
__global__ __launch_bounds__(64)
void prep_kernel(const float* __restrict__ z1, const float* __restrict__ z2,
                 const float* __restrict__ W1, const float* __restrict__ b1,
                 const float* __restrict__ W2,
                 float* __restrict__ Abuf, float* __restrict__ Bbuf,
                 unsigned short* __restrict__ W2f) {
  int blk = blockIdx.x, tid = threadIdx.x;
  if (blk < 1024) {
    int which = blk >> 9;                 // 0: A (z1,W1a,+b1)  1: B (z2,W1b)
    int t = blk & 511;
    int j0 = (t >> 3) << 4;               // 16-row tile (j or i)
    int g0 = (t & 7) << 4;                // 16-col g tile
    const float* z = which ? z2 : z1;
    __shared__ __align__(16) short zf[4 * 64 * 8];    // 4 KB z a-frags
    __shared__ __align__(16) short w1f[4 * 64 * 8];   // 4 KB W1 b-frags

    // z tile: 16 rows x 128 cols, 8 float4 per lane
#pragma unroll
    for (int p = 0; p < 8; ++p) {
      int u = p * 64 + tid;
      int row = u >> 5;                   // 0..15
      int c = (u & 31) * 4;               // 0..124
      float4v v = *(const float4v*)(z + (j0 + row) * EMB + c);
      int kt = c >> 5;
      int lane = ((c >> 3) & 3) * 16 + row;
      store_bf16x4(zf + (kt * 64 + lane) * 8 + (c & 7), v);
    }
    // W1 tile: 16 g-rows x 128 cols, 8 float4 per lane
    {
      const float* wbase = W1 + g0 * (2 * EMB) + which * EMB;
#pragma unroll
      for (int p = 0; p < 8; ++p) {
        int u = p * 64 + tid;
        int grow = u >> 5;                // 0..15
        int c = (u & 31) * 4;
        float4v v = *(const float4v*)(wbase + grow * (2 * EMB) + c);
        int kt = c >> 5;
        int lane = ((c >> 3) & 3) * 16 + grow;
        store_bf16x4(w1f + (kt * 64 + lane) * 8 + (c & 7), v);
      }
    }
    __syncthreads();

    int l = tid, r = l & 15, q = l >> 4;
    float4v acc = {};
#pragma unroll
    for (int kt = 0; kt < 4; ++kt) {
      short8 az = *(const short8*)(zf + (kt * 64 + l) * 8);
      short8 bf = *(const short8*)(w1f + (kt * 64 + l) * 8);
      acc = mfma16(az, bf, acc);
    }
    int gg = g0 + r;
    float ba = which ? 0.0f : b1[gg];
    float* dstp = which ? Bbuf : Abuf;
#pragma unroll
    for (int reg = 0; reg < 4; ++reg)
      dstp[(j0 + q * 4 + reg) * HID + gg] = acc[reg] + ba;
  } else {
    // W2f swizzle: 64 blocks x 64 threads x 4 shorts. Coalesced float4 reads,
    // scattered bf16 writes. Half-major layout: half p = nt>>2 at
    // [p*8192, +8192) shorts; within: ((kt*4 + (nt&3))*64 + lane)*8 + (h&7).
    int s0 = (blk - 1024) * 256 + tid * 4;
    float4v v0 = *(const float4v*)(W2 + s0);
    float vals[4] = {v0[0], v0[1], v0[2], v0[3]};
#pragma unroll
    for (int j = 0; j < 4; ++j) {
      int s = s0 + j;
      int g = s >> 7;
      int h = s & 127;
      int kt = h >> 5;
      int nt = g >> 4;
      int p = nt >> 2;
      int lane = ((h >> 3) & 3) * 16 + (g & 15);
      int dst = p * 8192 + ((kt * 4 + (nt & 3)) * 64 + lane) * 8 + (h & 7);
      unsigned u = __float_as_uint(vals[j]);
      W2f[dst] = (unsigned short)((u + 0x7FFFu + ((u >> 16) & 1u)) >> 16);  // RNE
    }
  }
}

// ---------------------------------------------------------------------------
// main: UNCHANGED from round 5 (104 us, passed, absmax 0.001037598).
// one block = 8i x 16j tile, 256 threads (4 waves), wave owns 2 i-rows.
// Swapped operands: D[g][pair] = W2 · h1^T.  TWO-PASS g-split (stash replay).
// W2 staged by async global_load_lds; intra-loop next-kt A/B prefetch.
// ---------------------------------------------------------------------------
__global__ __launch_bounds__(256, 4)
void fused_mlp_kernel(const float* __restrict__ Abuf, const float* __restrict__ Bbuf,
                      const float* __restrict__ W2f4,  // packed bf16 frags, half-major
                      const float* __restrict__ b2, const float* __restrict__ W3,
                      const float* __restrict__ b3, float* __restrict__ out) {
  __shared__ __align__(16) short s_w2[HID * HID];  // 32 KB, both halves

  int tid = threadIdx.x;
  int w = tid >> 6, l = tid & 63, r = l & 15, q = l >> 4;

  // async stage: 8 x 16B per thread, wave-linear dest — global_load_lds's
  // exact contract (uniform LDS base + lane*16; per-lane global src).
  {
    const float4v* wsrc = (const float4v*)W2f4;
    int wb = tid & 192;                       // wave-uniform base
#pragma unroll
    for (int t = 0; t < 8; ++t) {
      __builtin_amdgcn_global_load_lds(
          (const __attribute__((address_space(1))) void*)(wsrc + t * 256 + tid),
          (__attribute__((address_space(3))) void*)(s_w2 + (t * 256 + wb) * 8),
          16, 0, 0);
    }
  }

  int bi = (blockIdx.x >> 6) << 3;
  int bj = (blockIdx.x & 63) << 4;

  const float* Ap  = Abuf + (bj + r) * HID + q * 8;       // A'[j=bj+r]
  const float* Bp0 = Bbuf + (bi + 2 * w) * HID + q * 8;   // B[i0]
  const float* Bp1 = Bp0 + HID;                           // B[i1]

  short8 afs[4][2];                 // h1 frag stash: [kt][p], 32 VGPRs
  float2v s0l = {0.f, 0.f}, s0h = {0.f, 0.f};
  float2v s1l = {0.f, 0.f}, s1h = {0.f, 0.f};
  float4v acc[2][4];

  __syncthreads();                  // drains vmcnt: s_w2 fully staged

  // ---------------- pass 0: g in [0,64) ----------------
#pragma unroll
  for (int nt = 0; nt < 4; ++nt) {
    float4v bv = *(const float4v*)(b2 + nt * 16 + q * 4);
    acc[0][nt] = bv;
    acc[1][nt] = bv;
  }

  // preload kt=0 globals (post-barrier, round-0 structure)
  float4v a0  = *(const float4v*)(Ap);
  float4v a1  = *(const float4v*)(Ap + 4);
  float4v b00 = *(const float4v*)(Bp0);
  float4v b01 = *(const float4v*)(Bp0 + 4);
  float4v b10 = *(const float4v*)(Bp1);
  float4v b11 = *(const float4v*)(Bp1 + 4);

#pragma unroll
  for (int kt = 0; kt < 4; ++kt) {
    float4v ca0 = a0, ca1 = a1, cb00 = b00, cb01 = b01, cb10 = b10, cb11 = b11;
    if (kt < 3) {                       // issue next-kt loads before gelu chain
      int off = (kt + 1) * 32;
      a0  = *(const float4v*)(Ap + off);
      a1  = *(const float4v*)(Ap + off + 4);
      b00 = *(const float4v*)(Bp0 + off);
      b01 = *(const float4v*)(Bp0 + off + 4);
      b10 = *(const float4v*)(Bp1 + off);
      b11 = *(const float4v*)(Bp1 + off + 4);
    }
    float2v g0l, g0h, g1l, g1h;
    gelu4pk(lo2(ca0) + lo2(cb00), hi2(ca0) + hi2(cb00), g0l, g0h);
    gelu4pk(lo2(ca1) + lo2(cb01), hi2(ca1) + hi2(cb01), g1l, g1h);
    short8 af0 = to_bf16x8_pk(g0l, g0h, g1l, g1h);
    gelu4pk(lo2(ca0) + lo2(cb10), hi2(ca0) + hi2(cb10), g0l, g0h);
    gelu4pk(lo2(ca1) + lo2(cb11), hi2(ca1) + hi2(cb11), g1l, g1h);
    short8 af1 = to_bf16x8_pk(g0l, g0h, g1l, g1h);
    afs[kt][0] = af0;
    afs[kt][1] = af1;

    const short8* wrow = (const short8*)s_w2 + kt * 256 + l;   // half 0
#pragma unroll
    for (int nt = 0; nt < 4; ++nt) {
      short8 wf = wrow[nt * 64];        // stride-16B, conflict-free
      acc[0][nt] = mfma16(wf, af0, acc[0][nt]);
      acc[1][nt] = mfma16(wf, af1, acc[1][nt]);
    }
  }

#pragma unroll
  for (int nt = 0; nt < 4; ++nt) {
    float4v wv = *(const float4v*)(W3 + nt * 16 + q * 4);
    float2v g0l, g0h, g1l, g1h;
    gelu4pk(lo2(acc[0][nt]), hi2(acc[0][nt]), g0l, g0h);
    gelu4pk(lo2(acc[1][nt]), hi2(acc[1][nt]), g1l, g1h);
    s0l = s0l + g0l * lo2(wv);
    s0h = s0h + g0h * hi2(wv);
    s1l = s1l + g1l * lo2(wv);
    s1h = s1h + g1h * hi2(wv);
  }

  // ---------------- pass 1: g in [64,128) — stash replay, no gelu/VMEM ----
#pragma unroll
  for (int nt = 0; nt < 4; ++nt) {
    float4v bv = *(const float4v*)(b2 + (nt + 4) * 16 + q * 4);
    acc[0][nt] = bv;
    acc[1][nt] = bv;
  }
#pragma unroll
  for (int kt = 0; kt < 4; ++kt) {
    short8 af0 = afs[kt][0];
    short8 af1 = afs[kt][1];
    const short8* wrow = (const short8*)s_w2 + 1024 + kt * 256 + l;  // half 1
#pragma unroll
    for (int nt = 0; nt < 4; ++nt) {
      short8 wf = wrow[nt * 64];
      acc[0][nt] = mfma16(wf, af0, acc[0][nt]);
      acc[1][nt] = mfma16(wf, af1, acc[1][nt]);
    }
  }
#pragma unroll
  for (int nt = 0; nt < 4; ++nt) {
    float4v wv = *(const float4v*)(W3 + (nt + 4) * 16 + q * 4);
    float2v g0l, g0h, g1l, g1h;
    gelu4pk(lo2(acc[0][nt]), hi2(acc[0][nt]), g0l, g0h);
    gelu4pk(lo2(acc[1][nt]), hi2(acc[1][nt]), g1l, g1h);
    s0l = s0l + g0l * lo2(wv);
    s0h = s0h + g0h * hi2(wv);
    s1l = s1l + g1l * lo2(wv);
    s1h = s1h + g1h * hi2(wv);
  }

  // reduce + store
  float bias3 = b3[0];
  float sc0 = s0l[0] + s0l[1] + s0h[0] + s0h[1];
  float sc1 = s1l[0] + s1l[1] + s1h[0] + s1h[1];
  sc0 += __shfl_xor(sc0, 16, 64);
  sc0 += __shfl_xor(sc0, 32, 64);
  sc1 += __shfl_xor(sc1, 16, 64);
  sc1 += __shfl_xor(sc1, 32, 64);
  if (l < 16) {
    out[(bi + 2 * w) * NN + bj + l]     = sc0 + bias3;
    out[(bi + 2 * w + 1) * NN + bj + l] = sc1 + bias3;
  }
}

extern "C" void kernel_launch(void* const* d_in, const int* in_sizes, int n_in,
                              void* d_out, int out_size, void* d_ws, size_t ws_size,
                              hipStream_t stream) {
  const float* z1 = (const float*)d_in[0];
  const float* z2 = (const float*)d_in[1];
  const float* W1 = (const float*)d_in[2];
  const float* b1 = (const float*)d_in[3];
  const float* W2 = (const float*)d_in[4];
  const float* b2 = (const float*)d_in[5];
  const float* W3 = (const float*)d_in[6];
  const float* b3 = (const float*)d_in[7];
  float* out = (float*)d_out;

  float* Abuf = (float*)d_ws;                                // 512 KB
  float* Bbuf = Abuf + NN * HID;                             // 512 KB
  unsigned short* W2f = (unsigned short*)(Bbuf + NN * HID);  // 32 KB

  prep_kernel<<<1088, 64, 0, stream>>>(z1, z2, W1, b1, W2, Abuf, Bbuf, W2f);
  fused_mlp_kernel<<<(NN / 8) * (NN / 16), 256, 0, stream>>>(
      Abuf, Bbuf, (const float*)W2f, b2, W3, b3, out);
}

// Round 7
// 157.196 us; speedup vs baseline: 1.0029x; 1.0029x over previous
//
#include <hip/hip_runtime.h>

#define NN  1024
#define EMB 128
#define HID 128

typedef __attribute__((ext_vector_type(2))) float float2v;
typedef __attribute__((ext_vector_type(4))) float float4v;
typedef __attribute__((ext_vector_type(8))) float float8v;
typedef __attribute__((ext_vector_type(8))) short short8;
typedef __attribute__((ext_vector_type(4))) __bf16 bf16x4;
typedef __attribute__((ext_vector_type(8))) __bf16 bf16x8;

__device__ __forceinline__ float2v lo2(float4v v) { float2v r; r[0] = v[0]; r[1] = v[1]; return r; }
__device__ __forceinline__ float2v hi2(float4v v) { float2v r; r[0] = v[2]; r[1] = v[3]; return r; }

__device__ __forceinline__ short8 to_bf16x8_pk(float2v al, float2v ah, float2v bl, float2v bh) {
  float8v f = {al[0], al[1], ah[0], ah[1], bl[0], bl[1], bh[0], bh[1]};
  bf16x8 r = __builtin_convertvector(f, bf16x8);   // v_cvt_pk_bf16_f32 x4
  return __builtin_bit_cast(short8, r);
}

__device__ __forceinline__ void store_bf16x4(short* p, float4v v) {
  bf16x4 r = __builtin_convertvector(v, bf16x4);
  *(bf16x4*)p = r;
}

// tanh-form GELU on 4 elements as 2x float2v halves. Same op graph as round 0
// (absmax-identical): ONE v_rcp per 4 elements via shared reciprocal.
// d_i = 1+2^y >= 1, |x|<4.5 => product < 2^80: no overflow.
__device__ __forceinline__ void gelu4pk(float2v xl, float2v xh,
                                        float2v& ol, float2v& oh) {
  float2v x2l = xl * xl;
  float2v x2h = xh * xh;
  float2v tl = x2l * 0.1029432f + 2.3022086f;  // 2*sqrt(2/pi)*log2e*(1+0.044715x^2)
  float2v th = x2h * 0.1029432f + 2.3022086f;
  float2v yl = xl * tl;
  float2v yh = xh * th;
  float2v el, eh;
  el[0] = __builtin_amdgcn_exp2f(yl[0]);
  el[1] = __builtin_amdgcn_exp2f(yl[1]);
  eh[0] = __builtin_amdgcn_exp2f(yh[0]);
  eh[1] = __builtin_amdgcn_exp2f(yh[1]);
  float2v dl = el + 1.0f;
  float2v dh = eh + 1.0f;
  float p01 = dl[0] * dl[1];
  float p23 = dh[0] * dh[1];
  float rall = __builtin_amdgcn_rcpf(p01 * p23);
  float r01 = p23 * rall;                      // 1/(d0*d1)
  float r23 = p01 * rall;                      // 1/(d2*d3)
  float2v rvl, rvh;
  rvl[0] = dl[1] * r01;
  rvl[1] = dl[0] * r01;
  rvh[0] = dh[1] * r23;
  rvh[1] = dh[0] * r23;
  ol = xl - xl * rvl;                          // x*sigmoid(2*inner)
  oh = xh - xh * rvh;
}

__device__ __forceinline__ float4v mfma16(short8 a, short8 b, float4v c) {
  return __builtin_amdgcn_mfma_f32_16x16x32_bf16(a, b, c, 0, 0, 0);
}

// ---------------------------------------------------------------------------
// prep (unchanged from round 6): 1088 one-wave blocks.
//   blocks 0..511    -> A-part: Abuf[j0..j0+15, g0..g0+15] = z1·W1a + b1
//   blocks 512..1023 -> B-part: Bbuf[i0..i0+15, g0..g0+15] = z2·W1b
//   blocks 1024..1087-> W2f: bf16(W2) pre-swizzled, half-major frag order
// ---------------------------------------------------------------------------
__global__ __launch_bounds__(64)
void prep_kernel(const float* __restrict__ z1, const float* __restrict__ z2,
                 const float* __restrict__ W1, const float* __restrict__ b1,
                 const float* __restrict__ W2,
                 float* __restrict__ Abuf, float* __restrict__ Bbuf,
                 unsigned short* __restrict__ W2f) {
  int blk = blockIdx.x, tid = threadIdx.x;
  if (blk < 1024) {
    int which = blk >> 9;                 // 0: A (z1,W1a,+b1)  1: B (z2,W1b)
    int t = blk & 511;
    int j0 = (t >> 3) << 4;               // 16-row tile (j or i)
    int g0 = (t & 7) << 4;                // 16-col g tile
    const float* z = which ? z2 : z1;
    __shared__ __align__(16) short zf[4 * 64 * 8];    // 4 KB z a-frags
    __shared__ __align__(16) short w1f[4 * 64 * 8];   // 4 KB W1 b-frags

#pragma unroll
    for (int p = 0; p < 8; ++p) {
      int u = p * 64 + tid;
      int row = u >> 5;                   // 0..15
      int c = (u & 31) * 4;               // 0..124
      float4v v = *(const float4v*)(z + (j0 + row) * EMB + c);
      int kt = c >> 5;
      int lane = ((c >> 3) & 3) * 16 + row;
      store_bf16x4(zf + (kt * 64 + lane) * 8 + (c & 7), v);
    }
    {
      const float* wbase = W1 + g0 * (2 * EMB) + which * EMB;
#pragma unroll
      for (int p = 0; p < 8; ++p) {
        int u = p * 64 + tid;
        int grow = u >> 5;                // 0..15
        int c = (u & 31) * 4;
        float4v v = *(const float4v*)(wbase + grow * (2 * EMB) + c);
        int kt = c >> 5;
        int lane = ((c >> 3) & 3) * 16 + grow;
        store_bf16x4(w1f + (kt * 64 + lane) * 8 + (c & 7), v);
      }
    }
    __syncthreads();

    int l = tid, r = l & 15, q = l >> 4;
    float4v acc = {};
#pragma unroll
    for (int kt = 0; kt < 4; ++kt) {
      short8 az = *(const short8*)(zf + (kt * 64 + l) * 8);
      short8 bf = *(const short8*)(w1f + (kt * 64 + l) * 8);
      acc = mfma16(az, bf, acc);
    }
    int gg = g0 + r;
    float ba = which ? 0.0f : b1[gg];
    float* dstp = which ? Bbuf : Abuf;
#pragma unroll
    for (int reg = 0; reg < 4; ++reg)
      dstp[(j0 + q * 4 + reg) * HID + gg] = acc[reg] + ba;
  } else {
    // W2f swizzle. Half-major layout: half p = nt>>2 at [p*8192, +8192)
    // shorts; within: ((kt*4 + (nt&3))*64 + lane)*8 + (h&7).
    int s0 = (blk - 1024) * 256 + tid * 4;
    float4v v0 = *(const float4v*)(W2 + s0);
    float vals[4] = {v0[0], v0[1], v0[2], v0[3]};
#pragma unroll
    for (int j = 0; j < 4; ++j) {
      int s = s0 + j;
      int g = s >> 7;
      int h = s & 127;
      int kt = h >> 5;
      int nt = g >> 4;
      int p = nt >> 2;
      int lane = ((h >> 3) & 3) * 16 + (g & 15);
      int dst = p * 8192 + ((kt * 4 + (nt & 3)) * 64 + lane) * 8 + (h & 7);
      unsigned u = __float_as_uint(vals[j]);
      W2f[dst] = (unsigned short)((u + 0x7FFFu + ((u >> 16) & 1u)) >> 16);  // RNE
    }
  }
}

// ---------------------------------------------------------------------------
// main: one block = 8i x 16j tile, 256 threads (4 waves), wave owns 2 i-rows.
// Swapped operands: D[g][pair] = W2 · h1^T.  TWO-PASS g-split (stash replay).
// Round-7 change: HALF-STAGED 16 KB s_w2 (round-1 mechanism, which measured
// 51% occupancy vs 38% at 32 KB) WITHOUT round-1's two fatal flaws:
//   * launch_bounds stays (256,4) — the proven non-spilling RA target
//     (round 1's (256,5) spilled ~50 regs -> 600 MB scratch);
//   * half-1 restage via async global_load_lds (zero VGPR temps; round 1
//     round-tripped through 16 registers). Issue after the pass-0/pass-1
//     read barrier; pass-0 epilogue (~600+ cy of gelu VALU) hides latency.
// Everything else byte-identical to round 5/6 (104 us, absmax 0.001037598).
// Target: 4-5 blocks/CU resident -> fill the ~33 us of VALU issue-idle.
// ---------------------------------------------------------------------------
__global__ __launch_bounds__(256, 4)
void fused_mlp_kernel(const float* __restrict__ Abuf, const float* __restrict__ Bbuf,
                      const float* __restrict__ W2f4,  // packed bf16 frags, half-major
                      const float* __restrict__ b2, const float* __restrict__ W3,
                      const float* __restrict__ b3, float* __restrict__ out) {
  __shared__ __align__(16) short s_w2[64 * 128];  // 16 KB, one pass-half

  int tid = threadIdx.x;
  int w = tid >> 6, l = tid & 63, r = l & 15, q = l >> 4;

  const float4v* wsrc = (const float4v*)W2f4;
  int wb = tid & 192;                       // wave-uniform base

  // async stage of HALF 0: 4 x 16B per thread, wave-linear dest.
#pragma unroll
  for (int t = 0; t < 4; ++t) {
    __builtin_amdgcn_global_load_lds(
        (const __attribute__((address_space(1))) void*)(wsrc + t * 256 + tid),
        (__attribute__((address_space(3))) void*)(s_w2 + (t * 256 + wb) * 8),
        16, 0, 0);
  }

  int bi = (blockIdx.x >> 6) << 3;
  int bj = (blockIdx.x & 63) << 4;

  const float* Ap  = Abuf + (bj + r) * HID + q * 8;       // A'[j=bj+r]
  const float* Bp0 = Bbuf + (bi + 2 * w) * HID + q * 8;   // B[i0]
  const float* Bp1 = Bp0 + HID;                           // B[i1]

  short8 afs[4][2];                 // h1 frag stash: [kt][p], 32 VGPRs
  float2v s0l = {0.f, 0.f}, s0h = {0.f, 0.f};
  float2v s1l = {0.f, 0.f}, s1h = {0.f, 0.f};
  float4v acc[2][4];

  __syncthreads();                  // drains vmcnt: half 0 staged

  // ---------------- pass 0: g in [0,64) ----------------
#pragma unroll
  for (int nt = 0; nt < 4; ++nt) {
    float4v bv = *(const float4v*)(b2 + nt * 16 + q * 4);
    acc[0][nt] = bv;
    acc[1][nt] = bv;
  }

  // preload kt=0 globals (post-barrier, round-0 structure)
  float4v a0  = *(const float4v*)(Ap);
  float4v a1  = *(const float4v*)(Ap + 4);
  float4v b00 = *(const float4v*)(Bp0);
  float4v b01 = *(const float4v*)(Bp0 + 4);
  float4v b10 = *(const float4v*)(Bp1);
  float4v b11 = *(const float4v*)(Bp1 + 4);

#pragma unroll
  for (int kt = 0; kt < 4; ++kt) {
    float4v ca0 = a0, ca1 = a1, cb00 = b00, cb01 = b01, cb10 = b10, cb11 = b11;
    if (kt < 3) {                       // issue next-kt loads before gelu chain
      int off = (kt + 1) * 32;
      a0  = *(const float4v*)(Ap + off);
      a1  = *(const float4v*)(Ap + off + 4);
      b00 = *(const float4v*)(Bp0 + off);
      b01 = *(const float4v*)(Bp0 + off + 4);
      b10 = *(const float4v*)(Bp1 + off);
      b11 = *(const float4v*)(Bp1 + off + 4);
    }
    float2v g0l, g0h, g1l, g1h;
    gelu4pk(lo2(ca0) + lo2(cb00), hi2(ca0) + hi2(cb00), g0l, g0h);
    gelu4pk(lo2(ca1) + lo2(cb01), hi2(ca1) + hi2(cb01), g1l, g1h);
    short8 af0 = to_bf16x8_pk(g0l, g0h, g1l, g1h);
    gelu4pk(lo2(ca0) + lo2(cb10), hi2(ca0) + hi2(cb10), g0l, g0h);
    gelu4pk(lo2(ca1) + lo2(cb11), hi2(ca1) + hi2(cb11), g1l, g1h);
    short8 af1 = to_bf16x8_pk(g0l, g0h, g1l, g1h);
    afs[kt][0] = af0;
    afs[kt][1] = af1;

    const short8* wrow = (const short8*)s_w2 + kt * 256 + l;   // half 0
#pragma unroll
    for (int nt = 0; nt < 4; ++nt) {
      short8 wf = wrow[nt * 64];        // stride-16B, conflict-free
      acc[0][nt] = mfma16(wf, af0, acc[0][nt]);
      acc[1][nt] = mfma16(wf, af1, acc[1][nt]);
    }
  }

  // ---------------- restage s_w2 with HALF 1 (async) ----------------
  __syncthreads();                  // all waves done READING half 0
#pragma unroll
  for (int t = 0; t < 4; ++t) {
    __builtin_amdgcn_global_load_lds(
        (const __attribute__((address_space(1))) void*)(wsrc + 1024 + t * 256 + tid),
        (__attribute__((address_space(3))) void*)(s_w2 + (t * 256 + wb) * 8),
        16, 0, 0);
  }

  // pass-0 epilogue runs while half-1 loads are in flight (latency cover)
#pragma unroll
  for (int nt = 0; nt < 4; ++nt) {
    float4v wv = *(const float4v*)(W3 + nt * 16 + q * 4);
    float2v g0l, g0h, g1l, g1h;
    gelu4pk(lo2(acc[0][nt]), hi2(acc[0][nt]), g0l, g0h);
    gelu4pk(lo2(acc[1][nt]), hi2(acc[1][nt]), g1l, g1h);
    s0l = s0l + g0l * lo2(wv);
    s0h = s0h + g0h * hi2(wv);
    s1l = s1l + g1l * lo2(wv);
    s1h = s1h + g1h * hi2(wv);
  }

  __syncthreads();                  // drains vmcnt: half 1 staged

  // ---------------- pass 1: g in [64,128) — stash replay, no gelu/VMEM ----
#pragma unroll
  for (int nt = 0; nt < 4; ++nt) {
    float4v bv = *(const float4v*)(b2 + (nt + 4) * 16 + q * 4);
    acc[0][nt] = bv;
    acc[1][nt] = bv;
  }
#pragma unroll
  for (int kt = 0; kt < 4; ++kt) {
    short8 af0 = afs[kt][0];
    short8 af1 = afs[kt][1];
    const short8* wrow = (const short8*)s_w2 + kt * 256 + l;   // half 1 (restaged)
#pragma unroll
    for (int nt = 0; nt < 4; ++nt) {
      short8 wf = wrow[nt * 64];
      acc[0][nt] = mfma16(wf, af0, acc[0][nt]);
      acc[1][nt] = mfma16(wf, af1, acc[1][nt]);
    }
  }
#pragma unroll
  for (int nt = 0; nt < 4; ++nt) {
    float4v wv = *(const float4v*)(W3 + (nt + 4) * 16 + q * 4);
    float2v g0l, g0h, g1l, g1h;
    gelu4pk(lo2(acc[0][nt]), hi2(acc[0][nt]), g0l, g0h);
    gelu4pk(lo2(acc[1][nt]), hi2(acc[1][nt]), g1l, g1h);
    s0l = s0l + g0l * lo2(wv);
    s0h = s0h + g0h * hi2(wv);
    s1l = s1l + g1l * lo2(wv);
    s1h = s1h + g1h * hi2(wv);
  }

  // reduce + store
  float bias3 = b3[0];
  float sc0 = s0l[0] + s0l[1] + s0h[0] + s0h[1];
  float sc1 = s1l[0] + s1l[1] + s1h[0] + s1h[1];
  sc0 += __shfl_xor(sc0, 16, 64);
  sc0 += __shfl_xor(sc0, 32, 64);
  sc1 += __shfl_xor(sc1, 16, 64);
  sc1 += __shfl_xor(sc1, 32, 64);
  if (l < 16) {
    out[(bi + 2 * w) * NN + bj + l]     = sc0 + bias3;
    out[(bi + 2 * w + 1) * NN + bj + l] = sc1 + bias3;
  }
}

extern "C" void kernel_launch(void* const* d_in, const int* in_sizes, int n_in,
                              void* d_out, int out_size, void* d_ws, size_t ws_size,
                              hipStream_t stream) {
  const float* z1 = (const float*)d_in[0];
  const float* z2 = (const float*)d_in[1];
  const float* W1 = (const float*)d_in[2];
  const float* b1 = (const float*)d_in[3];
  const float* W2 = (const float*)d_in[4];
  const float* b2 = (const float*)d_in[5];
  const float* W3 = (const float*)d_in[6];
  const float* b3 = (const float*)d_in[7];
  float* out = (float*)d_out;

  float* Abuf = (float*)d_ws;                                // 512 KB
  float* Bbuf = Abuf + NN * HID;                             // 512 KB
  unsigned short* W2f = (unsigned short*)(Bbuf + NN * HID);  // 32 KB

  prep_kernel<<<1088, 64, 0, stream>>>(z1, z2, W1, b1, W2, Abuf, Bbuf, W2f);
  fused_mlp_kernel<<<(NN / 8) * (NN / 16), 256, 0, stream>>>(
      Abuf, Bbuf, (const float*)W2f, b2, W3, b3, out);
}

// Round 8
// 152.270 us; speedup vs baseline: 1.0353x; 1.0323x over previous
//
#include <hip/hip_runtime.h>

#define NN  1024
#define EMB 128
#define HID 128

typedef __attribute__((ext_vector_type(2))) float float2v;
typedef __attribute__((ext_vector_type(4))) float float4v;
typedef __attribute__((ext_vector_type(8))) float float8v;
typedef __attribute__((ext_vector_type(8))) short short8;
typedef __attribute__((ext_vector_type(4))) __bf16 bf16x4;
typedef __attribute__((ext_vector_type(8))) __bf16 bf16x8;

__device__ __forceinline__ float2v lo2(float4v v) { float2v r; r[0] = v[0]; r[1] = v[1]; return r; }
__device__ __forceinline__ float2v hi2(float4v v) { float2v r; r[0] = v[2]; r[1] = v[3]; return r; }

__device__ __forceinline__ short8 to_bf16x8_pk(float2v al, float2v ah, float2v bl, float2v bh) {
  float8v f = {al[0], al[1], ah[0], ah[1], bl[0], bl[1], bh[0], bh[1]};
  bf16x8 r = __builtin_convertvector(f, bf16x8);   // v_cvt_pk_bf16_f32 x4
  return __builtin_bit_cast(short8, r);
}

__device__ __forceinline__ void store_bf16x4(short* p, float4v v) {
  bf16x4 r = __builtin_convertvector(v, bf16x4);
  *(bf16x4*)p = r;
}

// tanh-form GELU, round-8 variant: PER-ELEMENT v_rcp instead of the shared-
// reciprocal trick. The shared trick traded 3 trans ops for 10 VALU ops per
// 4 elements — backwards on this kernel, where VALU issue is the measured
// bottleneck (VALUBusy 66%) and the trans pipe is ~94% idle. Per 4 elems:
// 20 VALU + 8 trans (was 28 + 5), and a 3-level-shorter dependency chain.
// Slightly MORE accurate than shared-rcp (fewer roundings).
__device__ __forceinline__ void gelu4r(float2v xl, float2v xh,
                                       float2v& ol, float2v& oh) {
  float2v x2l = xl * xl;
  float2v x2h = xh * xh;
  float2v tl = x2l * 0.1029432f + 2.3022086f;  // 2*sqrt(2/pi)*log2e*(1+0.044715x^2)
  float2v th = x2h * 0.1029432f + 2.3022086f;
  float2v yl = xl * tl;
  float2v yh = xh * th;
  float2v dl, dh;
  dl[0] = __builtin_amdgcn_exp2f(yl[0]) + 1.0f;
  dl[1] = __builtin_amdgcn_exp2f(yl[1]) + 1.0f;
  dh[0] = __builtin_amdgcn_exp2f(yh[0]) + 1.0f;
  dh[1] = __builtin_amdgcn_exp2f(yh[1]) + 1.0f;
  float2v rvl, rvh;
  rvl[0] = __builtin_amdgcn_rcpf(dl[0]);       // 1/(1+2^y) = sigmoid(-2*inner)
  rvl[1] = __builtin_amdgcn_rcpf(dl[1]);
  rvh[0] = __builtin_amdgcn_rcpf(dh[0]);
  rvh[1] = __builtin_amdgcn_rcpf(dh[1]);
  ol = xl - xl * rvl;                          // x*sigmoid(2*inner)
  oh = xh - xh * rvh;
}

__device__ __forceinline__ float4v mfma16(short8 a, short8 b, float4v c) {
  return __builtin_amdgcn_mfma_f32_16x16x32_bf16(a, b, c, 0, 0, 0);
}

// ---------------------------------------------------------------------------
// prep (unchanged from round 6): 1088 one-wave blocks.
//   blocks 0..511    -> A-part: Abuf[j0..j0+15, g0..g0+15] = z1·W1a + b1
//   blocks 512..1023 -> B-part: Bbuf[i0..i0+15, g0..g0+15] = z2·W1b
//   blocks 1024..1087-> W2f: bf16(W2) pre-swizzled, half-major frag order
// ---------------------------------------------------------------------------
__global__ __launch_bounds__(64)
void prep_kernel(const float* __restrict__ z1, const float* __restrict__ z2,
                 const float* __restrict__ W1, const float* __restrict__ b1,
                 const float* __restrict__ W2,
                 float* __restrict__ Abuf, float* __restrict__ Bbuf,
                 unsigned short* __restrict__ W2f) {
  int blk = blockIdx.x, tid = threadIdx.x;
  if (blk < 1024) {
    int which = blk >> 9;                 // 0: A (z1,W1a,+b1)  1: B (z2,W1b)
    int t = blk & 511;
    int j0 = (t >> 3) << 4;               // 16-row tile (j or i)
    int g0 = (t & 7) << 4;                // 16-col g tile
    const float* z = which ? z2 : z1;
    __shared__ __align__(16) short zf[4 * 64 * 8];    // 4 KB z a-frags
    __shared__ __align__(16) short w1f[4 * 64 * 8];   // 4 KB W1 b-frags

#pragma unroll
    for (int p = 0; p < 8; ++p) {
      int u = p * 64 + tid;
      int row = u >> 5;                   // 0..15
      int c = (u & 31) * 4;               // 0..124
      float4v v = *(const float4v*)(z + (j0 + row) * EMB + c);
      int kt = c >> 5;
      int lane = ((c >> 3) & 3) * 16 + row;
      store_bf16x4(zf + (kt * 64 + lane) * 8 + (c & 7), v);
    }
    {
      const float* wbase = W1 + g0 * (2 * EMB) + which * EMB;
#pragma unroll
      for (int p = 0; p < 8; ++p) {
        int u = p * 64 + tid;
        int grow = u >> 5;                // 0..15
        int c = (u & 31) * 4;
        float4v v = *(const float4v*)(wbase + grow * (2 * EMB) + c);
        int kt = c >> 5;
        int lane = ((c >> 3) & 3) * 16 + grow;
        store_bf16x4(w1f + (kt * 64 + lane) * 8 + (c & 7), v);
      }
    }
    __syncthreads();

    int l = tid, r = l & 15, q = l >> 4;
    float4v acc = {};
#pragma unroll
    for (int kt = 0; kt < 4; ++kt) {
      short8 az = *(const short8*)(zf + (kt * 64 + l) * 8);
      short8 bf = *(const short8*)(w1f + (kt * 64 + l) * 8);
      acc = mfma16(az, bf, acc);
    }
    int gg = g0 + r;
    float ba = which ? 0.0f : b1[gg];
    float* dstp = which ? Bbuf : Abuf;
#pragma unroll
    for (int reg = 0; reg < 4; ++reg)
      dstp[(j0 + q * 4 + reg) * HID + gg] = acc[reg] + ba;
  } else {
    // W2f swizzle. Half-major layout: half p = nt>>2 at [p*8192, +8192)
    // shorts; within: ((kt*4 + (nt&3))*64 + lane)*8 + (h&7).
    int s0 = (blk - 1024) * 256 + tid * 4;
    float4v v0 = *(const float4v*)(W2 + s0);
    float vals[4] = {v0[0], v0[1], v0[2], v0[3]};
#pragma unroll
    for (int j = 0; j < 4; ++j) {
      int s = s0 + j;
      int g = s >> 7;
      int h = s & 127;
      int kt = h >> 5;
      int nt = g >> 4;
      int p = nt >> 2;
      int lane = ((h >> 3) & 3) * 16 + (g & 15);
      int dst = p * 8192 + ((kt * 4 + (nt & 3)) * 64 + lane) * 8 + (h & 7);
      unsigned u = __float_as_uint(vals[j]);
      W2f[dst] = (unsigned short)((u + 0x7FFFu + ((u >> 16) & 1u)) >> 16);  // RNE
    }
  }
}

// ---------------------------------------------------------------------------
// main: one block = 8i x 16j tile, 256 threads (4 waves), wave owns 2 i-rows.
// Swapped operands: D[g][pair] = W2 · h1^T.  TWO-PASS g-split (stash replay),
// 16 KB half-staged s_w2 with async global_load_lds restage (round 7).
// Round-8 changes (instruction-stream attack; structure untouched):
//   * gelu4r: per-element v_rcp — 28 issue slots per 4 elems vs 33. Moves
//     work from the saturated VALU pipe to the ~idle trans pipe.
//   * kt=0 A/B preloads hoisted BEFORE the staging barrier: their latency
//     now hides under the barrier's vmcnt drain instead of stalling kt=0.
// ---------------------------------------------------------------------------
__global__ __launch_bounds__(256, 4)
void fused_mlp_kernel(const float* __restrict__ Abuf, const float* __restrict__ Bbuf,
                      const float* __restrict__ W2f4,  // packed bf16 frags, half-major
                      const float* __restrict__ b2, const float* __restrict__ W3,
                      const float* __restrict__ b3, float* __restrict__ out) {
  __shared__ __align__(16) short s_w2[64 * 128];  // 16 KB, one pass-half

  int tid = threadIdx.x;
  int w = tid >> 6, l = tid & 63, r = l & 15, q = l >> 4;

  const float4v* wsrc = (const float4v*)W2f4;
  int wb = tid & 192;                       // wave-uniform base

  // async stage of HALF 0: 4 x 16B per thread, wave-linear dest.
#pragma unroll
  for (int t = 0; t < 4; ++t) {
    __builtin_amdgcn_global_load_lds(
        (const __attribute__((address_space(1))) void*)(wsrc + t * 256 + tid),
        (__attribute__((address_space(3))) void*)(s_w2 + (t * 256 + wb) * 8),
        16, 0, 0);
  }

  int bi = (blockIdx.x >> 6) << 3;
  int bj = (blockIdx.x & 63) << 4;

  const float* Ap  = Abuf + (bj + r) * HID + q * 8;       // A'[j=bj+r]
  const float* Bp0 = Bbuf + (bi + 2 * w) * HID + q * 8;   // B[i0]
  const float* Bp1 = Bp0 + HID;                           // B[i1]

  short8 afs[4][2];                 // h1 frag stash: [kt][p], 32 VGPRs
  float2v s0l = {0.f, 0.f}, s0h = {0.f, 0.f};
  float2v s1l = {0.f, 0.f}, s1h = {0.f, 0.f};
  float4v acc[2][4];

  // kt=0 preloads issued BEFORE the barrier: latency hides under the
  // barrier's vmcnt drain of the LDS staging (Abuf/Bbuf written by the
  // previous dispatch — safe).
  float4v a0  = *(const float4v*)(Ap);
  float4v a1  = *(const float4v*)(Ap + 4);
  float4v b00 = *(const float4v*)(Bp0);
  float4v b01 = *(const float4v*)(Bp0 + 4);
  float4v b10 = *(const float4v*)(Bp1);
  float4v b11 = *(const float4v*)(Bp1 + 4);

  __syncthreads();                  // drains vmcnt: half 0 staged (+ preloads)

  // ---------------- pass 0: g in [0,64) ----------------
#pragma unroll
  for (int nt = 0; nt < 4; ++nt) {
    float4v bv = *(const float4v*)(b2 + nt * 16 + q * 4);
    acc[0][nt] = bv;
    acc[1][nt] = bv;
  }

#pragma unroll
  for (int kt = 0; kt < 4; ++kt) {
    float4v ca0 = a0, ca1 = a1, cb00 = b00, cb01 = b01, cb10 = b10, cb11 = b11;
    if (kt < 3) {                       // issue next-kt loads before gelu chain
      int off = (kt + 1) * 32;
      a0  = *(const float4v*)(Ap + off);
      a1  = *(const float4v*)(Ap + off + 4);
      b00 = *(const float4v*)(Bp0 + off);
      b01 = *(const float4v*)(Bp0 + off + 4);
      b10 = *(const float4v*)(Bp1 + off);
      b11 = *(const float4v*)(Bp1 + off + 4);
    }
    float2v g0l, g0h, g1l, g1h;
    gelu4r(lo2(ca0) + lo2(cb00), hi2(ca0) + hi2(cb00), g0l, g0h);
    gelu4r(lo2(ca1) + lo2(cb01), hi2(ca1) + hi2(cb01), g1l, g1h);
    short8 af0 = to_bf16x8_pk(g0l, g0h, g1l, g1h);
    gelu4r(lo2(ca0) + lo2(cb10), hi2(ca0) + hi2(cb10), g0l, g0h);
    gelu4r(lo2(ca1) + lo2(cb11), hi2(ca1) + hi2(cb11), g1l, g1h);
    short8 af1 = to_bf16x8_pk(g0l, g0h, g1l, g1h);
    afs[kt][0] = af0;
    afs[kt][1] = af1;

    const short8* wrow = (const short8*)s_w2 + kt * 256 + l;   // half 0
#pragma unroll
    for (int nt = 0; nt < 4; ++nt) {
      short8 wf = wrow[nt * 64];        // stride-16B, conflict-free
      acc[0][nt] = mfma16(wf, af0, acc[0][nt]);
      acc[1][nt] = mfma16(wf, af1, acc[1][nt]);
    }
  }

  // ---------------- restage s_w2 with HALF 1 (async) ----------------
  __syncthreads();                  // all waves done READING half 0
#pragma unroll
  for (int t = 0; t < 4; ++t) {
    __builtin_amdgcn_global_load_lds(
        (const __attribute__((address_space(1))) void*)(wsrc + 1024 + t * 256 + tid),
        (__attribute__((address_space(3))) void*)(s_w2 + (t * 256 + wb) * 8),
        16, 0, 0);
  }

  // pass-0 epilogue runs while half-1 loads are in flight (latency cover)
#pragma unroll
  for (int nt = 0; nt < 4; ++nt) {
    float4v wv = *(const float4v*)(W3 + nt * 16 + q * 4);
    float2v g0l, g0h, g1l, g1h;
    gelu4r(lo2(acc[0][nt]), hi2(acc[0][nt]), g0l, g0h);
    gelu4r(lo2(acc[1][nt]), hi2(acc[1][nt]), g1l, g1h);
    s0l = s0l + g0l * lo2(wv);
    s0h = s0h + g0h * hi2(wv);
    s1l = s1l + g1l * lo2(wv);
    s1h = s1h + g1h * hi2(wv);
  }

  __syncthreads();                  // drains vmcnt: half 1 staged

  // ---------------- pass 1: g in [64,128) — stash replay, no gelu/VMEM ----
#pragma unroll
  for (int nt = 0; nt < 4; ++nt) {
    float4v bv = *(const float4v*)(b2 + (nt + 4) * 16 + q * 4);
    acc[0][nt] = bv;
    acc[1][nt] = bv;
  }
#pragma unroll
  for (int kt = 0; kt < 4; ++kt) {
    short8 af0 = afs[kt][0];
    short8 af1 = afs[kt][1];
    const short8* wrow = (const short8*)s_w2 + kt * 256 + l;   // half 1 (restaged)
#pragma unroll
    for (int nt = 0; nt < 4; ++nt) {
      short8 wf = wrow[nt * 64];
      acc[0][nt] = mfma16(wf, af0, acc[0][nt]);
      acc[1][nt] = mfma16(wf, af1, acc[1][nt]);
    }
  }
#pragma unroll
  for (int nt = 0; nt < 4; ++nt) {
    float4v wv = *(const float4v*)(W3 + (nt + 4) * 16 + q * 4);
    float2v g0l, g0h, g1l, g1h;
    gelu4r(lo2(acc[0][nt]), hi2(acc[0][nt]), g0l, g0h);
    gelu4r(lo2(acc[1][nt]), hi2(acc[1][nt]), g1l, g1h);
    s0l = s0l + g0l * lo2(wv);
    s0h = s0h + g0h * hi2(wv);
    s1l = s1l + g1l * lo2(wv);
    s1h = s1h + g1h * hi2(wv);
  }

  // reduce + store
  float bias3 = b3[0];
  float sc0 = s0l[0] + s0l[1] + s0h[0] + s0h[1];
  float sc1 = s1l[0] + s1l[1] + s1h[0] + s1h[1];
  sc0 += __shfl_xor(sc0, 16, 64);
  sc0 += __shfl_xor(sc0, 32, 64);
  sc1 += __shfl_xor(sc1, 16, 64);
  sc1 += __shfl_xor(sc1, 32, 64);
  if (l < 16) {
    out[(bi + 2 * w) * NN + bj + l]     = sc0 + bias3;
    out[(bi + 2 * w + 1) * NN + bj + l] = sc1 + bias3;
  }
}

extern "C" void kernel_launch(void* const* d_in, const int* in_sizes, int n_in,
                              void* d_out, int out_size, void* d_ws, size_t ws_size,
                              hipStream_t stream) {
  const float* z1 = (const float*)d_in[0];
  const float* z2 = (const float*)d_in[1];
  const float* W1 = (const float*)d_in[2];
  const float* b1 = (const float*)d_in[3];
  const float* W2 = (const float*)d_in[4];
  const float* b2 = (const float*)d_in[5];
  const float* W3 = (const float*)d_in[6];
  const float* b3 = (const float*)d_in[7];
  float* out = (float*)d_out;

  float* Abuf = (float*)d_ws;                                // 512 KB
  float* Bbuf = Abuf + NN * HID;                             // 512 KB
  unsigned short* W2f = (unsigned short*)(Bbuf + NN * HID);  // 32 KB

  prep_kernel<<<1088, 64, 0, stream>>>(z1, z2, W1, b1, W2, Abuf, Bbuf, W2f);
  fused_mlp_kernel<<<(NN / 8) * (NN / 16), 256, 0, stream>>>(
      Abuf, Bbuf, (const float*)W2f, b2, W3, b3, out);
}

// Round 10
// 150.568 us; speedup vs baseline: 1.0470x; 1.0113x over previous
//
#include <hip/hip_runtime.h>

#define NN  1024
#define EMB 128
#define HID 128

typedef __attribute__((ext_vector_type(2))) float float2v;
typedef __attribute__((ext_vector_type(4))) float float4v;
typedef __attribute__((ext_vector_type(8))) float float8v;
typedef __attribute__((ext_vector_type(8))) short short8;
typedef __attribute__((ext_vector_type(4))) __bf16 bf16x4;
typedef __attribute__((ext_vector_type(8))) __bf16 bf16x8;

__device__ __forceinline__ float2v lo2(float4v v) { float2v r; r[0] = v[0]; r[1] = v[1]; return r; }
__device__ __forceinline__ float2v hi2(float4v v) { float2v r; r[0] = v[2]; r[1] = v[3]; return r; }

__device__ __forceinline__ short8 to_bf16x8_pk(float2v al, float2v ah, float2v bl, float2v bh) {
  float8v f = {al[0], al[1], ah[0], ah[1], bl[0], bl[1], bh[0], bh[1]};
  bf16x8 r = __builtin_convertvector(f, bf16x8);   // v_cvt_pk_bf16_f32 x4
  return __builtin_bit_cast(short8, r);
}

__device__ __forceinline__ void store_bf16x4(short* p, float4v v) {
  bf16x4 r = __builtin_convertvector(v, bf16x4);
  *(bf16x4*)p = r;
}

// tanh-form GELU (round-8 form, unchanged): PER-ELEMENT v_rcp. 5 VALU +
// 2 trans per element — the minimal op graph found so far. Per-element rcp
// beats the shared-reciprocal trick because the kernel is VALU-THROUGHPUT-
// bound while the trans pipe has slack (round 8: -5.7 us measured).
__device__ __forceinline__ void gelu4r(float2v xl, float2v xh,
                                       float2v& ol, float2v& oh) {
  float2v x2l = xl * xl;
  float2v x2h = xh * xh;
  float2v tl = x2l * 0.1029432f + 2.3022086f;  // 2*sqrt(2/pi)*log2e*(1+0.044715x^2)
  float2v th = x2h * 0.1029432f + 2.3022086f;
  float2v yl = xl * tl;
  float2v yh = xh * th;
  float2v dl, dh;
  dl[0] = __builtin_amdgcn_exp2f(yl[0]) + 1.0f;
  dl[1] = __builtin_amdgcn_exp2f(yl[1]) + 1.0f;
  dh[0] = __builtin_amdgcn_exp2f(yh[0]) + 1.0f;
  dh[1] = __builtin_amdgcn_exp2f(yh[1]) + 1.0f;
  float2v rvl, rvh;
  rvl[0] = __builtin_amdgcn_rcpf(dl[0]);       // 1/(1+2^y) = sigmoid(-2*inner)
  rvl[1] = __builtin_amdgcn_rcpf(dl[1]);
  rvh[0] = __builtin_amdgcn_rcpf(dh[0]);
  rvh[1] = __builtin_amdgcn_rcpf(dh[1]);
  ol = xl - xl * rvl;                          // x*sigmoid(2*inner)
  oh = xh - xh * rvh;
}

__device__ __forceinline__ float4v mfma16(short8 a, short8 b, float4v c) {
  return __builtin_amdgcn_mfma_f32_16x16x32_bf16(a, b, c, 0, 0, 0);
}

// ---------------------------------------------------------------------------
// prep (unchanged from round 6): 1088 one-wave blocks.
//   blocks 0..511    -> A-part: Abuf[j0..j0+15, g0..g0+15] = z1·W1a + b1
//   blocks 512..1023 -> B-part: Bbuf[i0..i0+15, g0..g0+15] = z2·W1b
//   blocks 1024..1087-> W2f: bf16(W2) pre-swizzled, half-major frag order
// ---------------------------------------------------------------------------
__global__ __launch_bounds__(64)
void prep_kernel(const float* __restrict__ z1, const float* __restrict__ z2,
                 const float* __restrict__ W1, const float* __restrict__ b1,
                 const float* __restrict__ W2,
                 float* __restrict__ Abuf, float* __restrict__ Bbuf,
                 unsigned short* __restrict__ W2f) {
  int blk = blockIdx.x, tid = threadIdx.x;
  if (blk < 1024) {
    int which = blk >> 9;                 // 0: A (z1,W1a,+b1)  1: B (z2,W1b)
    int t = blk & 511;
    int j0 = (t >> 3) << 4;               // 16-row tile (j or i)
    int g0 = (t & 7) << 4;                // 16-col g tile
    const float* z = which ? z2 : z1;
    __shared__ __align__(16) short zf[4 * 64 * 8];    // 4 KB z a-frags
    __shared__ __align__(16) short w1f[4 * 64 * 8];   // 4 KB W1 b-frags

#pragma unroll
    for (int p = 0; p < 8; ++p) {
      int u = p * 64 + tid;
      int row = u >> 5;                   // 0..15
      int c = (u & 31) * 4;               // 0..124
      float4v v = *(const float4v*)(z + (j0 + row) * EMB + c);
      int kt = c >> 5;
      int lane = ((c >> 3) & 3) * 16 + row;
      store_bf16x4(zf + (kt * 64 + lane) * 8 + (c & 7), v);
    }
    {
      const float* wbase = W1 + g0 * (2 * EMB) + which * EMB;
#pragma unroll
      for (int p = 0; p < 8; ++p) {
        int u = p * 64 + tid;
        int grow = u >> 5;                // 0..15
        int c = (u & 31) * 4;
        float4v v = *(const float4v*)(wbase + grow * (2 * EMB) + c);
        int kt = c >> 5;
        int lane = ((c >> 3) & 3) * 16 + grow;
        store_bf16x4(w1f + (kt * 64 + lane) * 8 + (c & 7), v);
      }
    }
    __syncthreads();

    int l = tid, r = l & 15, q = l >> 4;
    float4v acc = {};
#pragma unroll
    for (int kt = 0; kt < 4; ++kt) {
      short8 az = *(const short8*)(zf + (kt * 64 + l) * 8);
      short8 bf = *(const short8*)(w1f + (kt * 64 + l) * 8);
      acc = mfma16(az, bf, acc);
    }
    int gg = g0 + r;
    float ba = which ? 0.0f : b1[gg];
    float* dstp = which ? Bbuf : Abuf;
#pragma unroll
    for (int reg = 0; reg < 4; ++reg)
      dstp[(j0 + q * 4 + reg) * HID + gg] = acc[reg] + ba;
  } else {
    // W2f swizzle. Half-major layout: half p = nt>>2 at [p*8192, +8192)
    // shorts; within: ((kt*4 + (nt&3))*64 + lane)*8 + (h&7).
    int s0 = (blk - 1024) * 256 + tid * 4;
    float4v v0 = *(const float4v*)(W2 + s0);
    float vals[4] = {v0[0], v0[1], v0[2], v0[3]};
#pragma unroll
    for (int j = 0; j < 4; ++j) {
      int s = s0 + j;
      int g = s >> 7;
      int h = s & 127;
      int kt = h >> 5;
      int nt = g >> 4;
      int p = nt >> 2;
      int lane = ((h >> 3) & 3) * 16 + (g & 15);
      int dst = p * 8192 + ((kt * 4 + (nt & 3)) * 64 + lane) * 8 + (h & 7);
      unsigned u = __float_as_uint(vals[j]);
      W2f[dst] = (unsigned short)((u + 0x7FFFu + ((u >> 16) & 1u)) >> 16);  // RNE
    }
  }
}

// ---------------------------------------------------------------------------
// main: one block = 8i x 16j tile, 256 threads (4 waves), wave owns 2 i-rows.
// Swapped operands: D[g][pair] = W2 · h1^T.  TWO-PASS g-split (stash replay),
// 16 KB half-staged s_w2, async global_load_lds restage, hoisted preloads.
// Round-10 change (single knob): __launch_bounds__(256,4) -> (256,3).
// Evidence: occupancy is pinned at ~38% (3.04 waves/SIMD) in EVERY config —
// the 4-wave RA constraint (<=128 unified regs incl AGPRs) buys no residency
// while forcing the allocator into v_mov/recompute fat (VALU-busy 64 us vs
// ~25 us essential arithmetic). (256,3) gives RA ~170 regs of slack at the
// SAME residency. Arithmetic untouched: absmax must stay 0.001037598.
// Tripwires: WRITE_SIZE must stay 4096 KB; occupancy must not drop <28%.
// ---------------------------------------------------------------------------
__global__ __launch_bounds__(256, 3)
void fused_mlp_kernel(const float* __restrict__ Abuf, const float* __restrict__ Bbuf,
                      const float* __restrict__ W2f4,  // packed bf16 frags, half-major
                      const float* __restrict__ b2, const float* __restrict__ W3,
                      const float* __restrict__ b3, float* __restrict__ out) {
  __shared__ __align__(16) short s_w2[64 * 128];  // 16 KB, one pass-half

  int tid = threadIdx.x;
  int w = tid >> 6, l = tid & 63, r = l & 15, q = l >> 4;

  const float4v* wsrc = (const float4v*)W2f4;
  int wb = tid & 192;                       // wave-uniform base

  // async stage of HALF 0: 4 x 16B per thread, wave-linear dest.
#pragma unroll
  for (int t = 0; t < 4; ++t) {
    __builtin_amdgcn_global_load_lds(
        (const __attribute__((address_space(1))) void*)(wsrc + t * 256 + tid),
        (__attribute__((address_space(3))) void*)(s_w2 + (t * 256 + wb) * 8),
        16, 0, 0);
  }

  int bi = (blockIdx.x >> 6) << 3;
  int bj = (blockIdx.x & 63) << 4;

  const float* Ap  = Abuf + (bj + r) * HID + q * 8;       // A'[j=bj+r]
  const float* Bp0 = Bbuf + (bi + 2 * w) * HID + q * 8;   // B[i0]
  const float* Bp1 = Bp0 + HID;                           // B[i1]

  short8 afs[4][2];                 // h1 frag stash: [kt][p], 32 VGPRs
  float2v s0l = {0.f, 0.f}, s0h = {0.f, 0.f};
  float2v s1l = {0.f, 0.f}, s1h = {0.f, 0.f};
  float4v acc[2][4];

  // kt=0 preloads issued BEFORE the barrier: latency hides under the
  // barrier's vmcnt drain of the LDS staging (Abuf/Bbuf from prev dispatch).
  float4v a0  = *(const float4v*)(Ap);
  float4v a1  = *(const float4v*)(Ap + 4);
  float4v b00 = *(const float4v*)(Bp0);
  float4v b01 = *(const float4v*)(Bp0 + 4);
  float4v b10 = *(const float4v*)(Bp1);
  float4v b11 = *(const float4v*)(Bp1 + 4);

  __syncthreads();                  // drains vmcnt: half 0 staged (+ preloads)

  // ---------------- pass 0: g in [0,64) ----------------
#pragma unroll
  for (int nt = 0; nt < 4; ++nt) {
    float4v bv = *(const float4v*)(b2 + nt * 16 + q * 4);
    acc[0][nt] = bv;
    acc[1][nt] = bv;
  }

#pragma unroll
  for (int kt = 0; kt < 4; ++kt) {
    float4v ca0 = a0, ca1 = a1, cb00 = b00, cb01 = b01, cb10 = b10, cb11 = b11;
    if (kt < 3) {                       // issue next-kt loads before gelu chain
      int off = (kt + 1) * 32;
      a0  = *(const float4v*)(Ap + off);
      a1  = *(const float4v*)(Ap + off + 4);
      b00 = *(const float4v*)(Bp0 + off);
      b01 = *(const float4v*)(Bp0 + off + 4);
      b10 = *(const float4v*)(Bp1 + off);
      b11 = *(const float4v*)(Bp1 + off + 4);
    }
    float2v g0l, g0h, g1l, g1h;
    gelu4r(lo2(ca0) + lo2(cb00), hi2(ca0) + hi2(cb00), g0l, g0h);
    gelu4r(lo2(ca1) + lo2(cb01), hi2(ca1) + hi2(cb01), g1l, g1h);
    short8 af0 = to_bf16x8_pk(g0l, g0h, g1l, g1h);
    gelu4r(lo2(ca0) + lo2(cb10), hi2(ca0) + hi2(cb10), g0l, g0h);
    gelu4r(lo2(ca1) + lo2(cb11), hi2(ca1) + hi2(cb11), g1l, g1h);
    short8 af1 = to_bf16x8_pk(g0l, g0h, g1l, g1h);
    afs[kt][0] = af0;
    afs[kt][1] = af1;

    const short8* wrow = (const short8*)s_w2 + kt * 256 + l;   // half 0
#pragma unroll
    for (int nt = 0; nt < 4; ++nt) {
      short8 wf = wrow[nt * 64];        // stride-16B, conflict-free
      acc[0][nt] = mfma16(wf, af0, acc[0][nt]);
      acc[1][nt] = mfma16(wf, af1, acc[1][nt]);
    }
  }

  // ---------------- restage s_w2 with HALF 1 (async) ----------------
  __syncthreads();                  // all waves done READING half 0
#pragma unroll
  for (int t = 0; t < 4; ++t) {
    __builtin_amdgcn_global_load_lds(
        (const __attribute__((address_space(1))) void*)(wsrc + 1024 + t * 256 + tid),
        (__attribute__((address_space(3))) void*)(s_w2 + (t * 256 + wb) * 8),
        16, 0, 0);
  }

  // pass-0 epilogue runs while half-1 loads are in flight (latency cover)
#pragma unroll
  for (int nt = 0; nt < 4; ++nt) {
    float4v wv = *(const float4v*)(W3 + nt * 16 + q * 4);
    float2v g0l, g0h, g1l, g1h;
    gelu4r(lo2(acc[0][nt]), hi2(acc[0][nt]), g0l, g0h);
    gelu4r(lo2(acc[1][nt]), hi2(acc[1][nt]), g1l, g1h);
    s0l = s0l + g0l * lo2(wv);
    s0h = s0h + g0h * hi2(wv);
    s1l = s1l + g1l * lo2(wv);
    s1h = s1h + g1h * hi2(wv);
  }

  __syncthreads();                  // drains vmcnt: half 1 staged

  // ---------------- pass 1: g in [64,128) — stash replay, no gelu/VMEM ----
#pragma unroll
  for (int nt = 0; nt < 4; ++nt) {
    float4v bv = *(const float4v*)(b2 + (nt + 4) * 16 + q * 4);
    acc[0][nt] = bv;
    acc[1][nt] = bv;
  }
#pragma unroll
  for (int kt = 0; kt < 4; ++kt) {
    short8 af0 = afs[kt][0];
    short8 af1 = afs[kt][1];
    const short8* wrow = (const short8*)s_w2 + kt * 256 + l;   // half 1 (restaged)
#pragma unroll
    for (int nt = 0; nt < 4; ++nt) {
      short8 wf = wrow[nt * 64];
      acc[0][nt] = mfma16(wf, af0, acc[0][nt]);
      acc[1][nt] = mfma16(wf, af1, acc[1][nt]);
    }
  }
#pragma unroll
  for (int nt = 0; nt < 4; ++nt) {
    float4v wv = *(const float4v*)(W3 + (nt + 4) * 16 + q * 4);
    float2v g0l, g0h, g1l, g1h;
    gelu4r(lo2(acc[0][nt]), hi2(acc[0][nt]), g0l, g0h);
    gelu4r(lo2(acc[1][nt]), hi2(acc[1][nt]), g1l, g1h);
    s0l = s0l + g0l * lo2(wv);
    s0h = s0h + g0h * hi2(wv);
    s1l = s1l + g1l * lo2(wv);
    s1h = s1h + g1h * hi2(wv);
  }

  // reduce + store
  float bias3 = b3[0];
  float sc0 = s0l[0] + s0l[1] + s0h[0] + s0h[1];
  float sc1 = s1l[0] + s1l[1] + s1h[0] + s1h[1];
  sc0 += __shfl_xor(sc0, 16, 64);
  sc0 += __shfl_xor(sc0, 32, 64);
  sc1 += __shfl_xor(sc1, 16, 64);
  sc1 += __shfl_xor(sc1, 32, 64);
  if (l < 16) {
    out[(bi + 2 * w) * NN + bj + l]     = sc0 + bias3;
    out[(bi + 2 * w + 1) * NN + bj + l] = sc1 + bias3;
  }
}

extern "C" void kernel_launch(void* const* d_in, const int* in_sizes, int n_in,
                              void* d_out, int out_size, void* d_ws, size_t ws_size,
                              hipStream_t stream) {
  const float* z1 = (const float*)d_in[0];
  const float* z2 = (const float*)d_in[1];
  const float* W1 = (const float*)d_in[2];
  const float* b1 = (const float*)d_in[3];
  const float* W2 = (const float*)d_in[4];
  const float* b2 = (const float*)d_in[5];
  const float* W3 = (const float*)d_in[6];
  const float* b3 = (const float*)d_in[7];
  float* out = (float*)d_out;

  float* Abuf = (float*)d_ws;                                // 512 KB
  float* Bbuf = Abuf + NN * HID;                             // 512 KB
  unsigned short* W2f = (unsigned short*)(Bbuf + NN * HID);  // 32 KB

  prep_kernel<<<1088, 64, 0, stream>>>(z1, z2, W1, b1, W2, Abuf, Bbuf, W2f);
  fused_mlp_kernel<<<(NN / 8) * (NN / 16), 256, 0, stream>>>(
      Abuf, Bbuf, (const float*)W2f, b2, W3, b3, out);
}